// Round 1
// 3807.505 us; speedup vs baseline: 3.9006x; 3.9006x over previous
//
#include <hip/hip_runtime.h>
#include <hip/hip_bf16.h>

// ---------- types ----------
typedef short s8v __attribute__((ext_vector_type(8)));   // 8 bf16 in 4 VGPRs
typedef float f4v __attribute__((ext_vector_type(4)));
typedef int   i4v __attribute__((ext_vector_type(4)));

__device__ inline unsigned short f2bf(float f) {
  union { float f; unsigned int u; } v; v.f = f;
  unsigned int r = (v.u + 0x7fffu + ((v.u >> 16) & 1u)) >> 16;  // RNE
  return (unsigned short)r;
}
__device__ inline float bf2f(unsigned short h) {
  union { unsigned int u; float f; } v; v.u = ((unsigned int)h) << 16;
  return v.f;
}

// ---------------------------------------------------------------------------
// Phase 1: xV = x @ Vw^T + Vb.  Unchanged from previous round (~300us, 2%).
// ---------------------------------------------------------------------------
__global__ __launch_bounds__(256) void gemm_xv(const float* __restrict__ x,
                                               const float* __restrict__ Vw,
                                               const float* __restrict__ Vb,
                                               float* __restrict__ out) {
  __shared__ unsigned short As[128][40];
  __shared__ unsigned short Bs[128][40];
  const int tid  = threadIdx.x;
  const int lane = tid & 63;
  const int wv   = tid >> 6;
  const int wm   = wv & 1, wn = wv >> 1;
  const int q    = lane >> 4, mr = lane & 15;
  const int rowBase = blockIdx.y * 128;
  const int colBase = blockIdx.x * 128;

  f4v acc[4][4] = {};

  for (int k0 = 0; k0 < 512; k0 += 32) {
#pragma unroll
    for (int r = 0; r < 4; ++r) {
      int idx = tid + (r << 8);
      int arow = idx >> 3, ac = idx & 7;
      const float4 av = *(const float4*)(x + (size_t)(rowBase + arow) * 512 + k0 + (ac << 2));
      ushort4 ap;
      ap.x = f2bf(av.x); ap.y = f2bf(av.y); ap.z = f2bf(av.z); ap.w = f2bf(av.w);
      *(ushort4*)&As[arow][ac << 2] = ap;
      const float4 bv = *(const float4*)(Vw + (size_t)(colBase + arow) * 512 + k0 + (ac << 2));
      ushort4 bp;
      bp.x = f2bf(bv.x); bp.y = f2bf(bv.y); bp.z = f2bf(bv.z); bp.w = f2bf(bv.w);
      *(ushort4*)&Bs[arow][ac << 2] = bp;
    }
    __syncthreads();
    s8v af[4], bf_[4];
#pragma unroll
    for (int mt = 0; mt < 4; ++mt)
      af[mt] = *(const s8v*)&As[wm * 64 + mt * 16 + mr][q * 8];
#pragma unroll
    for (int nt = 0; nt < 4; ++nt)
      bf_[nt] = *(const s8v*)&Bs[wn * 64 + nt * 16 + mr][q * 8];
#pragma unroll
    for (int mt = 0; mt < 4; ++mt)
#pragma unroll
      for (int nt = 0; nt < 4; ++nt)
        acc[mt][nt] = __builtin_amdgcn_mfma_f32_16x16x32_bf16(af[mt], bf_[nt], acc[mt][nt], 0, 0, 0);
    __syncthreads();
  }

#pragma unroll
  for (int nt = 0; nt < 4; ++nt) {
    int col = colBase + wn * 64 + nt * 16 + mr;
    float vb = Vb[col];
#pragma unroll
    for (int mt = 0; mt < 4; ++mt) {
      int row0 = rowBase + wm * 64 + mt * 16 + q * 4;
#pragma unroll
      for (int e = 0; e < 4; ++e)
        out[(size_t)(row0 + e) * 512 + col] = acc[mt][nt][e] + vb;
    }
  }
}

// ---------------------------------------------------------------------------
// Phase 2: persistent recurrence, wave-synchronous, fence-free.
//
// 16 bands (16 batch rows each) x 8 slices (64 H cols each) = 128 blocks.
// Each of the 4 waves in a block owns 16 output cols with FULL K=512:
//   - W slice (split bf16: hi + residual) lives in 128 VGPRs/lane, preloaded.
//   - no LDS, no __syncthreads, no __threadfence anywhere in the loop.
// h is exchanged via the memory-side Infinity Cache with explicit sc0 sc1
// (bypass L1+L2) loads/stores -> coherent across XCDs with NO cache
// maintenance. Release = s_waitcnt vmcnt(0) (stores acked at the coherent
// point) + per-wave agent-scope flag store. Acquire = poll 32 band flags
// (32 lanes, one each) + sc0 sc1 data loads.
// Ping-pong h buffers: flag>=t+1 implies that wave finished READING step t's
// input, so overwriting buffer (t-1)&1 at step t+1 is safe.
// ---------------------------------------------------------------------------
#define GLD16(dst, base, OFS)                                              \
  asm volatile("global_load_dwordx4 %0, %1, off offset:" #OFS " sc0 sc1"   \
               : "=v"(dst) : "v"(base) : "memory")
#define GST2(base, OFS, val)                                               \
  asm volatile("global_store_short %0, %1, off offset:" #OFS " sc0 sc1"    \
               :: "v"(base), "v"(val) : "memory")
#define LD2(S, OFS) GLD16(va1[S], p1, OFS); GLD16(va2[S], p2, OFS)

__global__ __launch_bounds__(256, 1) void rnn_steps(const float* __restrict__ Ww,
                                                    const float* __restrict__ Wb,
                                                    float* __restrict__ out,
                                                    unsigned short* __restrict__ hb1,
                                                    unsigned short* __restrict__ hb2,
                                                    int* __restrict__ arrive) {
  const int band  = blockIdx.x >> 3;   // 16 bands of 16 batch rows
  const int slice = blockIdx.x & 7;    // 8 slices of 64 H cols
  const int tid   = threadIdx.x;
  const int lane  = tid & 63;
  const int wv    = tid >> 6;          // wave owns cols [slice*64+wv*16, +16)
  const int q = lane >> 4, mr = lane & 15;

  const int col  = (slice << 6) + (wv << 4) + mr;  // this lane's output col
  const int row0 = (band << 4) + (q << 2);         // first of 4 output rows

  // ---- preload W fragments (split bf16) for full K=512: 128 VGPRs ----
  s8v w1[16], w2[16];
  {
    const float* wp0 = Ww + (size_t)col * 512 + (q << 3);
#pragma unroll
    for (int s = 0; s < 16; ++s) {
      const float* wp = wp0 + s * 32;
      s8v v1, v2;
#pragma unroll
      for (int e = 0; e < 8; ++e) {
        float f = wp[e];
        unsigned short a = f2bf(f);
        unsigned short b = f2bf(f - bf2f(a));
        v1[e] = (short)a; v2[e] = (short)b;
      }
      w1[s] = v1; w2[s] = v2;
    }
  }
  const float wb = Wb[col];
  float* outLast = out + (size_t)512 * 131072;

  int* flagp = arrive + band * 32 + (slice << 2) + wv;   // my per-wave flag
  int* fpoll = arrive + band * 32 + (lane & 31);         // lane<32 polls one flag
  const size_t hofs = (size_t)((band << 4) + mr) * 512 + (q << 3);  // A-frag base

  for (int t = 0; t < 512; ++t) {
    // xv prefetch — independent of h, issued BEFORE the flag wait.
    const size_t ob = (size_t)t * 131072 + (size_t)row0 * 512 + col;
    float xv0 = out[ob], xv1 = out[ob + 512], xv2 = out[ob + 1024], xv3 = out[ob + 1536];

    f4v accA = {}, accB = {}, accC = {};
    if (t > 0) {
      const size_t pofs = (size_t)((t - 1) & 1) * 131072;
      const unsigned short* p1 = hb1 + pofs + hofs;
      const unsigned short* p2 = hb2 + pofs + hofs;
      // acquire: all 32 waves of this band finished step t-1
      int guard = 0;
      for (;;) {
        int f = (lane < 32) ? __hip_atomic_load(fpoll, __ATOMIC_RELAXED,
                                                __HIP_MEMORY_SCOPE_AGENT) : t;
        if (__all(f >= t)) break;
        __builtin_amdgcn_s_sleep(1);
        if (++guard > (1 << 20)) break;   // safety: never hang the bench
      }
      // 32 independent IC-direct 16B loads, single drain.
      i4v va1[16], va2[16];
      LD2(0, 0);    LD2(1, 64);   LD2(2, 128);  LD2(3, 192);
      LD2(4, 256);  LD2(5, 320);  LD2(6, 384);  LD2(7, 448);
      LD2(8, 512);  LD2(9, 576);  LD2(10, 640); LD2(11, 704);
      LD2(12, 768); LD2(13, 832); LD2(14, 896); LD2(15, 960);
      asm volatile("s_waitcnt vmcnt(0)" ::: "memory");
      __builtin_amdgcn_sched_barrier(0);  // keep MFMAs below the waitcnt
#pragma unroll
      for (int s = 0; s < 16; ++s) {
        s8v a1 = __builtin_bit_cast(s8v, va1[s]);
        s8v a2 = __builtin_bit_cast(s8v, va2[s]);
        accA = __builtin_amdgcn_mfma_f32_16x16x32_bf16(a1, w1[s], accA, 0, 0, 0);
        accB = __builtin_amdgcn_mfma_f32_16x16x32_bf16(a1, w2[s], accB, 0, 0, 0);
        accC = __builtin_amdgcn_mfma_f32_16x16x32_bf16(a2, w1[s], accC, 0, 0, 0);
      }
    }

    // epilogue: z = hW + xv + b, tanh, split-bf16 h for the next step.
    float vx[4] = { xv0, xv1, xv2, xv3 };
    float vo[4]; unsigned int hw1a[4], hw2a[4];
#pragma unroll
    for (int e = 0; e < 4; ++e) {
      float z = ((accA[e] + accB[e]) + accC[e]) + vx[e] + wb;
      float v = tanhf(z);
      vo[e] = v;
      unsigned short h1 = f2bf(v);
      unsigned short h2 = f2bf(v - bf2f(h1));
      hw1a[e] = h1; hw2a[e] = h2;
    }
    out[ob] = vo[0]; out[ob + 512] = vo[1]; out[ob + 1024] = vo[2]; out[ob + 1536] = vo[3];
    if (t == 511) {
      size_t lb = (size_t)row0 * 512 + col;
      outLast[lb] = vo[0]; outLast[lb + 512] = vo[1];
      outLast[lb + 1024] = vo[2]; outLast[lb + 1536] = vo[3];
    }
    const size_t par = (size_t)(t & 1) * 131072;
    unsigned short* b1 = hb1 + par + (size_t)row0 * 512 + col;
    unsigned short* b2 = hb2 + par + (size_t)row0 * 512 + col;
    GST2(b1, 0, hw1a[0]); GST2(b1, 1024, hw1a[1]); GST2(b1, 2048, hw1a[2]); GST2(b1, 3072, hw1a[3]);
    GST2(b2, 0, hw2a[0]); GST2(b2, 1024, hw2a[1]); GST2(b2, 2048, hw2a[2]); GST2(b2, 3072, hw2a[3]);
    // release: wave's sc0sc1 stores acked at the coherent point, then flag.
    asm volatile("s_waitcnt vmcnt(0)" ::: "memory");
    if (lane == 0)
      __hip_atomic_store(flagp, t + 1, __ATOMIC_RELAXED, __HIP_MEMORY_SCOPE_AGENT);
  }
}

// ---------------------------------------------------------------------------
extern "C" void kernel_launch(void* const* d_in, const int* in_sizes, int n_in,
                              void* d_out, int out_size, void* d_ws, size_t ws_size,
                              hipStream_t stream) {
  const float* x  = (const float*)d_in[0];
  const float* Vw = (const float*)d_in[1];
  const float* Vb = (const float*)d_in[2];
  const float* Ww = (const float*)d_in[3];
  const float* Wb = (const float*)d_in[4];
  float* out = (float*)d_out;

  // ws layout: [0,4096) per-wave flags (16 bands x 32 waves, 4B each),
  // then h ping-pong bf16 splits (2 x 131072 ushorts each).
  int* arrive = (int*)d_ws;
  unsigned short* hb1 = (unsigned short*)((char*)d_ws + 4096);
  unsigned short* hb2 = (unsigned short*)((char*)d_ws + 4096 + 2 * 131072 * sizeof(unsigned short));

  hipMemsetAsync(d_ws, 0, 4096, stream);        // zero flags (ws is poisoned)
  gemm_xv<<<dim3(4, 1024), 256, 0, stream>>>(x, Vw, Vb, out);
  rnn_steps<<<dim3(128), 256, 0, stream>>>(Ww, Wb, out, hb1, hb2, arrive);
}